// Round 1
// baseline (37778.107 us; speedup 1.0000x reference)
//
#include <hip/hip_runtime.h>
#include <hip/hip_fp16.h>

// LSTM N=64, T=1024, D=1024, H=1024. fp32 in/out, fp16 MFMA compute, fp32 accum.
//
//  k_cvt_x    : x fp32 -> x16 fp16
//  k_cvt_h0   : h0 fp32 -> h16 buf0 fp16
//  k_tr_wx    : Wx (1024x4096) -> WxT fp16 (4096x1024)
//  k_pack_wh  : Wh -> per-block/wave/fragment-ordered fp16 pack (register-resident B)
//  k_gemm_xw  : xw16[t][n][4096] = x16 @ WxT^T   (m97-style 128x128x64 MFMA GEMM)
//  k_lstm     : persistent 64-block kernel, 1024 steps.
//               CHANGED vs prev round: central atomic barrier (single-line RMW
//               contention, ~25us/step) replaced by distributed per-block flags:
//               release-store own flag, all waves poll all 64 flags with ONE
//               per-lane load. 3 syncthreads/step. h stores widened to 8B.
//               h-fragment loads 2-deep pipelined. Ared padded 64->68.

typedef _Float16 f16x8 __attribute__((ext_vector_type(8)));
typedef _Float16 f16x4 __attribute__((ext_vector_type(4)));
typedef float    f32x4 __attribute__((ext_vector_type(4)));

#define LN 64
#define LT 1024
#define LD 1024
#define LH 1024
#define G4 4096

// workspace layout (bytes)
#define OFF_BAR  ((size_t)0)                                 // 64 flags * 128B = 8192
#define OFF_H16  ((size_t)8192)                              // 2 x 64 x 1024 fp16 ping-pong
#define OFF_X16  (OFF_H16 + (size_t)2*LN*LH*2)
#define OFF_WXT  (OFF_X16 + (size_t)LN*LT*LD*2)
#define OFF_WHP  (OFF_WXT + (size_t)LD*G4*2)
#define OFF_XW   (OFF_WHP + (size_t)LH*G4*2)
#define WS_NEED  (OFF_XW  + (size_t)LN*LT*G4*2)

#define ARS 68   // Ared row stride (floats): 64 + 4 pad -> f32x4 gate reads 2-way (free)

__device__ __forceinline__ float fast_sigmoid(float x) {
  float e = __expf(-fabsf(x));
  float s = __fdividef(e, 1.f + e);
  return x >= 0.f ? 1.f - s : s;
}
__device__ __forceinline__ float fast_tanh(float x) {
  float e = __expf(-2.f * fabsf(x));
  float t = __fdividef(1.f - e, 1.f + e);
  return x >= 0.f ? t : -t;
}

// ---------------- converts / packs ----------------

__global__ void k_cvt_x(const float* __restrict__ x, _Float16* __restrict__ x16) {
  size_t i = (size_t)blockIdx.x * 256 + threadIdx.x;   // one float4 per thread
  float4 v = ((const float4*)x)[i];
  f16x4 o;
  o[0] = (_Float16)v.x; o[1] = (_Float16)v.y; o[2] = (_Float16)v.z; o[3] = (_Float16)v.w;
  ((f16x4*)x16)[i] = o;
}

__global__ void k_cvt_h0(const float* __restrict__ h0, _Float16* __restrict__ h16) {
  int i = blockIdx.x * 256 + threadIdx.x;              // 65536 total
  h16[i] = (_Float16)h0[i];
}

__global__ void k_tr_wx(const float* __restrict__ Wx, _Float16* __restrict__ WxT) {
  __shared__ float tile[64][65];
  const int c0 = blockIdx.x * 64;   // col in 4096
  const int d0 = blockIdx.y * 64;   // row in 1024
  const int tx = threadIdx.x & 63, ty = threadIdx.x >> 6;
  for (int r = ty; r < 64; r += 4)
    tile[r][tx] = Wx[(size_t)(d0 + r) * G4 + c0 + tx];
  __syncthreads();
  for (int r = ty; r < 64; r += 4)
    WxT[(size_t)(c0 + r) * LD + d0 + tx] = (_Float16)tile[tx][r];
}

// dest unit u = (((bid*4 + w)*4 + g)*8 + kc)*64 + lane, each unit = 8 fp16 (16B)
__global__ void k_pack_wh(const float* __restrict__ Wh, _Float16* __restrict__ whp) {
  unsigned u = blockIdx.x * 256 + threadIdx.x;         // 524288 total
  int lane = u & 63; unsigned r = u >> 6;
  int kc = r & 7; r >>= 3;
  int g  = r & 3; r >>= 2;
  int w  = r & 3;
  int bid = r >> 2;
  int col = g * 1024 + bid * 16 + (lane & 15);
  int k0  = w * 256 + kc * 32 + (lane >> 4) * 8;
  f16x8 v;
#pragma unroll
  for (int j = 0; j < 8; ++j) v[j] = (_Float16)Wh[(size_t)(k0 + j) * G4 + col];
  ((f16x8*)whp)[u] = v;
}

// ---------------- phase-1 GEMM: xw = x @ Wx ----------------

__device__ __forceinline__ void gl_lds16(const _Float16* g, _Float16* l) {
  __builtin_amdgcn_global_load_lds(
      (const __attribute__((address_space(1))) unsigned int*)g,
      (__attribute__((address_space(3))) unsigned int*)l, 16, 0, 0);
}

__global__ __launch_bounds__(256) void k_gemm_xw(const _Float16* __restrict__ A,  // [65536][1024]
                                                 const _Float16* __restrict__ B,  // [4096][1024]
                                                 _Float16* __restrict__ C) {      // [t][n][4096]
  __shared__ _Float16 As[128 * 64];
  __shared__ _Float16 Bs[128 * 64];
  const int tid = threadIdx.x;
  const int lane = tid & 63;
  const int w = tid >> 6;
  const int wm = w & 1, wn = w >> 1;
  const int m0 = blockIdx.x * 128;
  const int n0 = blockIdx.y * 128;
  const int lr = lane >> 3;          // row 0..7 within an 8-row chunk
  const int lcb = (lane & 7) * 8;    // k element offset within 64

  f32x4 acc[4][4];
#pragma unroll
  for (int i = 0; i < 4; ++i)
#pragma unroll
    for (int j = 0; j < 4; ++j) acc[i][j] = (f32x4){0.f, 0.f, 0.f, 0.f};

  for (int kt = 0; kt < 16; ++kt) {
    const int k0 = kt * 64;
#pragma unroll
    for (int c2 = 0; c2 < 4; ++c2) {
      int chunk = w * 4 + c2;        // 0..15, 8 rows each
      int row = chunk * 8 + lr;
      gl_lds16(&A[(size_t)(m0 + row) * LD + k0 + lcb], &As[chunk * 512]);
      gl_lds16(&B[(size_t)(n0 + row) * LD + k0 + lcb], &Bs[chunk * 512]);
    }
    __syncthreads();
#pragma unroll
    for (int kc = 0; kc < 2; ++kc) {
      const int ko = kc * 32 + (lane >> 4) * 8;
      f16x8 Af[4], Bf[4];
#pragma unroll
      for (int mt = 0; mt < 4; ++mt)
        Af[mt] = *(const f16x8*)&As[(wm * 64 + mt * 16 + (lane & 15)) * 64 + ko];
#pragma unroll
      for (int nt = 0; nt < 4; ++nt)
        Bf[nt] = *(const f16x8*)&Bs[(wn * 64 + nt * 16 + (lane & 15)) * 64 + ko];
#pragma unroll
      for (int mt = 0; mt < 4; ++mt)
#pragma unroll
        for (int nt = 0; nt < 4; ++nt)
          acc[mt][nt] = __builtin_amdgcn_mfma_f32_16x16x32_f16(Af[mt], Bf[nt], acc[mt][nt], 0, 0, 0);
    }
    __syncthreads();
  }
  // epilogue: C[(t*64+n)*4096 + col] fp16, m = n*1024 + t
#pragma unroll
  for (int mt = 0; mt < 4; ++mt) {
#pragma unroll
    for (int nt = 0; nt < 4; ++nt) {
      int col = n0 + wn * 64 + nt * 16 + (lane & 15);
#pragma unroll
      for (int r = 0; r < 4; ++r) {
        int m = m0 + wm * 64 + mt * 16 + (lane >> 4) * 4 + r;
        int n = m >> 10, t = m & 1023;
        C[((size_t)t * 64 + n) * G4 + col] = (_Float16)acc[mt][nt][r];
      }
    }
  }
}

// ---------------- persistent recurrent kernel ----------------

__global__ __launch_bounds__(256, 1) void k_lstm(
    const _Float16* __restrict__ whp, const _Float16* __restrict__ xw,
    const float* __restrict__ bias, _Float16* h16, float* __restrict__ out,
    unsigned int* __restrict__ flags) {
  const int tid = threadIdx.x, bid = blockIdx.x;
  const int lane = tid & 63, w = tid >> 6;
  // gate-phase mapping: thread owns batch row gb and 4 consecutive h-cols
  const int gb = tid >> 2, gq = tid & 3;
  __shared__ float Ared[64 * ARS];   // [b 0..63][gcol 0..63] fp32, padded rows

  // B fragments: Wh slice, register-resident for the whole kernel.
  f16x8 Bf[4][8];
  {
    const f16x8* bp = (const f16x8*)whp + ((size_t)(bid * 4 + w) * 32) * 64 + lane;
#pragma unroll
    for (int g = 0; g < 4; ++g)
#pragma unroll
      for (int kc = 0; kc < 8; ++kc) Bf[g][kc] = bp[(g * 8 + kc) * 64];
  }
  f32x4 bvv[4];
#pragma unroll
  for (int g = 0; g < 4; ++g)
    bvv[g] = *(const f32x4*)&bias[g * 1024 + bid * 16 + gq * 4];
  float cst[4] = {0.f, 0.f, 0.f, 0.f};

  for (int i = tid; i < (64 * ARS) / 4; i += 256) ((f32x4*)Ared)[i] = (f32x4){0.f, 0.f, 0.f, 0.f};

  const int arow = lane & 15;
  const int kbase = w * 256 + (lane >> 4) * 8;
  int p = 0;

  for (int t = 0; t < LT; ++t) {
    // prefetch this step's xw slice (consumed after the reduce barrier;
    // HBM latency hides under the flag poll)
    f16x4 xwv[4];
    {
      const _Float16* xwp = xw + ((size_t)t * 64 + gb) * G4 + bid * 16 + gq * 4;
#pragma unroll
      for (int g = 0; g < 4; ++g) xwv[g] = *(const f16x4*)&xwp[(size_t)g * 1024];
    }

    // distributed barrier: wait until all 64 blocks have published step t.
    // One per-lane load polls ALL flags in a single memory round trip.
    if (t) {
      const unsigned want = (unsigned)t;
      while (__any(__hip_atomic_load(&flags[lane * 32], __ATOMIC_RELAXED,
                                     __HIP_MEMORY_SCOPE_AGENT) < want))
        __builtin_amdgcn_s_sleep(1);
    }
    __syncthreads();   // joins waves after poll; orders prev-step Ared re-zero before atomics
    __builtin_amdgcn_fence(__ATOMIC_ACQUIRE, "agent");  // invalidate stale h lines

    const _Float16* hc = h16 + (size_t)p * (LN * LH);
    f32x4 acc[4][4];
#pragma unroll
    for (int i = 0; i < 4; ++i)
#pragma unroll
      for (int j = 0; j < 4; ++j) acc[i][j] = (f32x4){0.f, 0.f, 0.f, 0.f};

    // h @ Wh with 2-deep pipelined fragment loads (h comes from IF$ post-fence)
#define LDH(kc, mt) (*(const f16x8*)&hc[((mt) * 16 + arow) * LH + kbase + (kc) * 32])
    {
      f16x8 Afa[4], Afb[4];
#pragma unroll
      for (int mt = 0; mt < 4; ++mt) Afa[mt] = LDH(0, mt);
#pragma unroll
      for (int kp = 0; kp < 4; ++kp) {
#pragma unroll
        for (int mt = 0; mt < 4; ++mt) Afb[mt] = LDH(2 * kp + 1, mt);
#pragma unroll
        for (int mt = 0; mt < 4; ++mt)
#pragma unroll
          for (int g = 0; g < 4; ++g)
            acc[mt][g] = __builtin_amdgcn_mfma_f32_16x16x32_f16(Afa[mt], Bf[g][2 * kp], acc[mt][g], 0, 0, 0);
        if (kp < 3) {
#pragma unroll
          for (int mt = 0; mt < 4; ++mt) Afa[mt] = LDH(2 * kp + 2, mt);
        }
#pragma unroll
        for (int mt = 0; mt < 4; ++mt)
#pragma unroll
          for (int g = 0; g < 4; ++g)
            acc[mt][g] = __builtin_amdgcn_mfma_f32_16x16x32_f16(Afb[mt], Bf[g][2 * kp + 1], acc[mt][g], 0, 0, 0);
      }
    }
#undef LDH

    // cross-wave K reduction via LDS atomic adds (staggered to cut collisions)
#pragma unroll
    for (int mi = 0; mi < 4; ++mi) {
      int mt = (mi + w) & 3;
#pragma unroll
      for (int gi = 0; gi < 4; ++gi) {
        int g = (gi + w) & 3;
#pragma unroll
        for (int r = 0; r < 4; ++r)
          atomicAdd(&Ared[(mt * 16 + (lane >> 4) * 4 + r) * ARS + g * 16 + (lane & 15)],
                    acc[mt][g][r]);
      }
    }
    __syncthreads();

    // gates: thread owns (b = gb, hcols = bid*16 + gq*4 .. +3), c state in registers
    _Float16* hn = h16 + (size_t)(p ^ 1) * (LN * LH);
    {
      f32x4 Ag[4];
#pragma unroll
      for (int g = 0; g < 4; ++g) {
        f32x4 r = *(const f32x4*)&Ared[gb * ARS + g * 16 + gq * 4];
        f32x4 xf;
#pragma unroll
        for (int j = 0; j < 4; ++j) xf[j] = (float)xwv[g][j];
        Ag[g] = r + xf + bvv[g];
      }
      f16x4 hv4;
      f32x4 o4;
#pragma unroll
      for (int j = 0; j < 4; ++j) {
        float iv = fast_sigmoid(Ag[0][j]);
        float fv = fast_sigmoid(Ag[1][j]);
        float ov = fast_sigmoid(Ag[2][j]);
        float gv = fast_tanh(Ag[3][j]);
        float cn = fv * cst[j] + iv * gv;
        cst[j] = cn;
        float hv = ov * fast_tanh(cn);
        hv4[j] = (_Float16)hv;
        o4[j] = hv;
      }
      union { f16x4 v; unsigned long long u; } cvt;
      cvt.v = hv4;
      // single 8B agent-scope (write-through) store so other XCDs see fresh h
      __hip_atomic_store((unsigned long long*)&hn[gb * 1024 + bid * 16 + gq * 4], cvt.u,
                         __ATOMIC_RELAXED, __HIP_MEMORY_SCOPE_AGENT);
      __builtin_nontemporal_store(o4, (f32x4*)&out[((size_t)gb * 1024 + t) * 1024 + bid * 16 + gq * 4]);
    }
    __syncthreads();   // drains all waves' h stores (vmcnt0 before s_barrier) + Ared reads done

    // publish: our h slice for step t+1 is visible -> release our flag
    if (tid == 0)
      __hip_atomic_store(&flags[bid * 32], (unsigned)(t + 1), __ATOMIC_RELEASE,
                         __HIP_MEMORY_SCOPE_AGENT);

    // re-zero Ared while other blocks finish (ordered vs next atomics by loop-top barrier)
    for (int i = tid; i < (64 * ARS) / 4; i += 256) ((f32x4*)Ared)[i] = (f32x4){0.f, 0.f, 0.f, 0.f};
    p ^= 1;
  }
}

// ---------------- launch ----------------

extern "C" void kernel_launch(void* const* d_in, const int* in_sizes, int n_in,
                              void* d_out, int out_size, void* d_ws, size_t ws_size,
                              hipStream_t stream) {
  const float* x  = (const float*)d_in[0];
  const float* h0 = (const float*)d_in[1];
  const float* Wx = (const float*)d_in[2];
  const float* Wh = (const float*)d_in[3];
  const float* b  = (const float*)d_in[4];
  float* out = (float*)d_out;
  char* ws = (char*)d_ws;
  if (ws_size < WS_NEED) return;  // insufficient scratch: bail (shows as poison absmax)

  unsigned int* flags = (unsigned int*)(ws + OFF_BAR);
  _Float16* h16 = (_Float16*)(ws + OFF_H16);
  _Float16* x16 = (_Float16*)(ws + OFF_X16);
  _Float16* wxT = (_Float16*)(ws + OFF_WXT);
  _Float16* whp = (_Float16*)(ws + OFF_WHP);
  _Float16* xw  = (_Float16*)(ws + OFF_XW);

  hipMemsetAsync(flags, 0, 8192, stream);
  hipLaunchKernelGGL(k_cvt_x,   dim3(65536),   dim3(256), 0, stream, x, x16);
  hipLaunchKernelGGL(k_cvt_h0,  dim3(256),     dim3(256), 0, stream, h0, h16);
  hipLaunchKernelGGL(k_tr_wx,   dim3(64, 16),  dim3(256), 0, stream, Wx, wxT);
  hipLaunchKernelGGL(k_pack_wh, dim3(2048),    dim3(256), 0, stream, Wh, whp);
  hipLaunchKernelGGL(k_gemm_xw, dim3(512, 32), dim3(256), 0, stream, x16, wxT, xw);
  hipLaunchKernelGGL(k_lstm,    dim3(64),      dim3(256), 0, stream, whp, xw, b, h16, out, flags);
}

// Round 2
// 27002.631 us; speedup vs baseline: 1.3991x; 1.3991x over previous
//
#include <hip/hip_runtime.h>
#include <hip/hip_fp16.h>

// LSTM N=64, T=1024, D=1024, H=1024. fp32 in/out, fp16 MFMA compute, fp32 accum.
//
//  k_cvt_x    : x fp32 -> x16 fp16
//  k_cvt_h0   : h0 fp32 -> h16 buf0 fp16
//  k_tr_wx    : Wx (1024x4096) -> WxT fp16 (4096x1024)
//  k_pack_wh  : Wh -> per-block/wave/fragment-ordered fp16 pack (register-resident B)
//  k_gemm_xw  : xw16[t][n][4096] = x16 @ WxT^T   (m97-style 128x128x64 MFMA GEMM)
//  k_lstm     : persistent 64-block kernel, 1024 steps, QUARTER-SKEWED systolic sync.
//               CHANGED vs prev round: (a) no release fences (round-1's per-step
//               buffer_wbl2 caused +4.2GB WRITE_SIZE and +5us/step); all cross-block
//               traffic via sc0 sc1 (coherence-point) asm loads/stores, ordering by
//               s_waitcnt vmcnt(0) before relaxed flag store (round-0-proven).
//               (b) the per-step full barrier is split into 4 batch-row-quarter
//               mini-barriers: quarter-q flags for step t were posted a full step
//               earlier, so steady-state waits are ~0 and the h propagation latency
//               hides under the other quarters' MFMA work (systolic skew).

typedef _Float16 f16x8 __attribute__((ext_vector_type(8)));
typedef _Float16 f16x4 __attribute__((ext_vector_type(4)));
typedef float    f32x4 __attribute__((ext_vector_type(4)));

#define LN 64
#define LT 1024
#define LD 1024
#define LH 1024
#define G4 4096

// workspace layout (bytes)
#define OFF_BAR  ((size_t)0)                                 // 64 src * 128B lines; flag[src*32 + q]
#define OFF_H16  ((size_t)8192)                              // 2 x 64 x 1024 fp16 ping-pong
#define OFF_X16  (OFF_H16 + (size_t)2*LN*LH*2)
#define OFF_WXT  (OFF_X16 + (size_t)LN*LT*LD*2)
#define OFF_WHP  (OFF_WXT + (size_t)LD*G4*2)
#define OFF_XW   (OFF_WHP + (size_t)LH*G4*2)
#define WS_NEED  (OFF_XW  + (size_t)LN*LT*G4*2)

#define ARS 68   // Ared row stride (floats): 64 + 4 pad

__device__ __forceinline__ float fast_sigmoid(float x) {
  float e = __expf(-fabsf(x));
  float s = __fdividef(e, 1.f + e);
  return x >= 0.f ? 1.f - s : s;
}
__device__ __forceinline__ float fast_tanh(float x) {
  float e = __expf(-2.f * fabsf(x));
  float t = __fdividef(1.f - e, 1.f + e);
  return x >= 0.f ? t : -t;
}

// ---------------- converts / packs ----------------

__global__ void k_cvt_x(const float* __restrict__ x, _Float16* __restrict__ x16) {
  size_t i = (size_t)blockIdx.x * 256 + threadIdx.x;   // one float4 per thread
  float4 v = ((const float4*)x)[i];
  f16x4 o;
  o[0] = (_Float16)v.x; o[1] = (_Float16)v.y; o[2] = (_Float16)v.z; o[3] = (_Float16)v.w;
  ((f16x4*)x16)[i] = o;
}

__global__ void k_cvt_h0(const float* __restrict__ h0, _Float16* __restrict__ h16) {
  int i = blockIdx.x * 256 + threadIdx.x;              // 65536 total
  h16[i] = (_Float16)h0[i];
}

__global__ void k_tr_wx(const float* __restrict__ Wx, _Float16* __restrict__ WxT) {
  __shared__ float tile[64][65];
  const int c0 = blockIdx.x * 64;   // col in 4096
  const int d0 = blockIdx.y * 64;   // row in 1024
  const int tx = threadIdx.x & 63, ty = threadIdx.x >> 6;
  for (int r = ty; r < 64; r += 4)
    tile[r][tx] = Wx[(size_t)(d0 + r) * G4 + c0 + tx];
  __syncthreads();
  for (int r = ty; r < 64; r += 4)
    WxT[(size_t)(c0 + r) * LD + d0 + tx] = (_Float16)tile[tx][r];
}

// dest unit u = (((bid*4 + w)*4 + g)*8 + kc)*64 + lane, each unit = 8 fp16 (16B)
__global__ void k_pack_wh(const float* __restrict__ Wh, _Float16* __restrict__ whp) {
  unsigned u = blockIdx.x * 256 + threadIdx.x;         // 524288 total
  int lane = u & 63; unsigned r = u >> 6;
  int kc = r & 7; r >>= 3;
  int g  = r & 3; r >>= 2;
  int w  = r & 3;
  int bid = r >> 2;
  int col = g * 1024 + bid * 16 + (lane & 15);
  int k0  = w * 256 + kc * 32 + (lane >> 4) * 8;
  f16x8 v;
#pragma unroll
  for (int j = 0; j < 8; ++j) v[j] = (_Float16)Wh[(size_t)(k0 + j) * G4 + col];
  ((f16x8*)whp)[u] = v;
}

// ---------------- phase-1 GEMM: xw = x @ Wx ----------------

__device__ __forceinline__ void gl_lds16(const _Float16* g, _Float16* l) {
  __builtin_amdgcn_global_load_lds(
      (const __attribute__((address_space(1))) unsigned int*)g,
      (__attribute__((address_space(3))) unsigned int*)l, 16, 0, 0);
}

__global__ __launch_bounds__(256) void k_gemm_xw(const _Float16* __restrict__ A,  // [65536][1024]
                                                 const _Float16* __restrict__ B,  // [4096][1024]
                                                 _Float16* __restrict__ C) {      // [t][n][4096]
  __shared__ _Float16 As[128 * 64];
  __shared__ _Float16 Bs[128 * 64];
  const int tid = threadIdx.x;
  const int lane = tid & 63;
  const int w = tid >> 6;
  const int wm = w & 1, wn = w >> 1;
  const int m0 = blockIdx.x * 128;
  const int n0 = blockIdx.y * 128;
  const int lr = lane >> 3;          // row 0..7 within an 8-row chunk
  const int lcb = (lane & 7) * 8;    // k element offset within 64

  f32x4 acc[4][4];
#pragma unroll
  for (int i = 0; i < 4; ++i)
#pragma unroll
    for (int j = 0; j < 4; ++j) acc[i][j] = (f32x4){0.f, 0.f, 0.f, 0.f};

  for (int kt = 0; kt < 16; ++kt) {
    const int k0 = kt * 64;
#pragma unroll
    for (int c2 = 0; c2 < 4; ++c2) {
      int chunk = w * 4 + c2;        // 0..15, 8 rows each
      int row = chunk * 8 + lr;
      gl_lds16(&A[(size_t)(m0 + row) * LD + k0 + lcb], &As[chunk * 512]);
      gl_lds16(&B[(size_t)(n0 + row) * LD + k0 + lcb], &Bs[chunk * 512]);
    }
    __syncthreads();
#pragma unroll
    for (int kc = 0; kc < 2; ++kc) {
      const int ko = kc * 32 + (lane >> 4) * 8;
      f16x8 Af[4], Bf[4];
#pragma unroll
      for (int mt = 0; mt < 4; ++mt)
        Af[mt] = *(const f16x8*)&As[(wm * 64 + mt * 16 + (lane & 15)) * 64 + ko];
#pragma unroll
      for (int nt = 0; nt < 4; ++nt)
        Bf[nt] = *(const f16x8*)&Bs[(wn * 64 + nt * 16 + (lane & 15)) * 64 + ko];
#pragma unroll
      for (int mt = 0; mt < 4; ++mt)
#pragma unroll
        for (int nt = 0; nt < 4; ++nt)
          acc[mt][nt] = __builtin_amdgcn_mfma_f32_16x16x32_f16(Af[mt], Bf[nt], acc[mt][nt], 0, 0, 0);
    }
    __syncthreads();
  }
  // epilogue: C[(t*64+n)*4096 + col] fp16, m = n*1024 + t
#pragma unroll
  for (int mt = 0; mt < 4; ++mt) {
#pragma unroll
    for (int nt = 0; nt < 4; ++nt) {
      int col = n0 + wn * 64 + nt * 16 + (lane & 15);
#pragma unroll
      for (int r = 0; r < 4; ++r) {
        int m = m0 + wm * 64 + mt * 16 + (lane >> 4) * 4 + r;
        int n = m >> 10, t = m & 1023;
        C[((size_t)t * 64 + n) * G4 + col] = (_Float16)acc[mt][nt][r];
      }
    }
  }
}

// ---------------- coherence-point access helpers (no fences, no L2 nukes) ----------------

// 16B load bypassing L1/L2 (reads at agent coherence point; sees write-through stores)
__device__ __forceinline__ f16x8 ldg_cohx8(const _Float16* p) {
  f16x8 r;
  asm volatile("global_load_dwordx4 %0, %1, off sc0 sc1" : "=v"(r) : "v"(p));
  return r;
}
// flag poll: coherent 4B load, completed before returning
__device__ __forceinline__ unsigned ldg_flag(const unsigned* p) {
  unsigned r;
  asm volatile("global_load_dword %0, %1, off sc0 sc1\n\ts_waitcnt vmcnt(0)"
               : "=v"(r) : "v"(p) : "memory");
  return r;
}
// 8B write-through store (visible at coherence point once vmcnt-retired)
__device__ __forceinline__ void stg_coh8(_Float16* p, f16x4 v) {
  asm volatile("global_store_dwordx2 %0, %1, off sc0 sc1" :: "v"(p), "v"(v) : "memory");
}
// flag publish: drain all prior vmem (h stores) THEN store flag write-through.
__device__ __forceinline__ void stg_flag(unsigned* p, unsigned v) {
  asm volatile("s_waitcnt vmcnt(0)\n\tglobal_store_dword %0, %1, off sc0 sc1"
               :: "v"(p), "v"(v) : "memory");
}

// ---------------- persistent recurrent kernel ----------------
//
// 64 blocks x 256 thr. Block bid owns h cols [bid*16, bid*16+16) (64 gate cols).
// Wave w consumes K-slice cols [w*256,(w+1)*256) = outputs of blocks 16w..16w+15.
// Batch rows split into 4 quarters; quarter q rows = 16q..16q+15, gate-owned by wave q.
// flag[src*32+q] = v  means  "h rows 16q..16q+15, cols src*16.., for step v are visible".

__global__ __launch_bounds__(256, 1) void k_lstm(
    const _Float16* __restrict__ whp, const _Float16* __restrict__ xw,
    const float* __restrict__ bias, _Float16* h16, float* __restrict__ out,
    unsigned int* __restrict__ flags) {
  const int tid = threadIdx.x, bid = blockIdx.x;
  const int lane = tid & 63, w = tid >> 6;
  const int arow = lane & 15;                  // A-fragment row within quarter / flag src idx
  const int kbase = w * 256 + (lane >> 4) * 8; // this wave's K-slice fragment base
  const int rg = lane >> 2, cg = lane & 3;     // gate phase: row-in-quarter, col-group
  __shared__ float Ared[4 * 16 * ARS];         // per-quarter [16][ARS] reduce regions

  // B fragments: Wh slice, register-resident for the whole kernel.
  f16x8 Bf[4][8];
  {
    const f16x8* bp = (const f16x8*)whp + ((size_t)(bid * 4 + w) * 32) * 64 + lane;
#pragma unroll
    for (int g = 0; g < 4; ++g)
#pragma unroll
      for (int kc = 0; kc < 8; ++kc) Bf[g][kc] = bp[(g * 8 + kc) * 64];
  }
  f32x4 bvv[4];
#pragma unroll
  for (int g = 0; g < 4; ++g)
    bvv[g] = *(const f32x4*)&bias[g * 1024 + bid * 16 + cg * 4];
  f32x4 cst = (f32x4){0.f, 0.f, 0.f, 0.f};     // c-state for (row=16w+rg, cols cg*4..)

  for (int i = tid; i < (4 * 16 * ARS) / 4; i += 256)
    ((f32x4*)Ared)[i] = (f32x4){0.f, 0.f, 0.f, 0.f};
  __syncthreads();

  const unsigned* fpoll = flags + (w * 16 + arow) * 32;   // + q per quarter

  for (int t = 0; t < LT; ++t) {
    const _Float16* hc = h16 + (size_t)(t & 1) * (LN * LH);
    _Float16*       hn = h16 + (size_t)((t & 1) ^ 1) * (LN * LH);
#pragma unroll
    for (int q = 0; q < 4; ++q) {
      // wait for this wave's 16 source blocks to publish quarter-q rows of h_t.
      // Steady state: these flags were posted a full step ago -> no spin.
      {
        const unsigned want = (unsigned)t;
        while (__any(ldg_flag(fpoll + q) < want)) __builtin_amdgcn_s_sleep(1);
      }
      // A fragments: h_t rows 16q+arow, this wave's K-slice (coherence-point loads)
      const _Float16* hrow = hc + (size_t)(q * 16 + arow) * LH + kbase;
      f16x8 Af[8];
#pragma unroll
      for (int kc = 0; kc < 8; ++kc) Af[kc] = ldg_cohx8(hrow + kc * 32);
      // xw prefetch for this quarter's gate owner (rides the same vmcnt drain)
      f16x4 xwv[4];
      if (w == q) {
        const _Float16* xwp = xw + ((size_t)t * 64 + q * 16 + rg) * G4 + bid * 16 + cg * 4;
#pragma unroll
        for (int g = 0; g < 4; ++g) xwv[g] = *(const f16x4*)&xwp[(size_t)g * 1024];
      }
      asm volatile("s_waitcnt vmcnt(0)" ::: "memory");
      __builtin_amdgcn_sched_barrier(0);

      f32x4 acc[4];
#pragma unroll
      for (int g = 0; g < 4; ++g) acc[g] = (f32x4){0.f, 0.f, 0.f, 0.f};
#pragma unroll
      for (int kc = 0; kc < 8; ++kc)
#pragma unroll
        for (int g = 0; g < 4; ++g)
          acc[g] = __builtin_amdgcn_mfma_f32_16x16x32_f16(Af[kc], Bf[g][kc], acc[g], 0, 0, 0);

      // cross-wave K reduction into this quarter's Ared region (all indices static)
      float* Aq = &Ared[q * 16 * ARS];
#pragma unroll
      for (int g = 0; g < 4; ++g)
#pragma unroll
        for (int r = 0; r < 4; ++r)
          atomicAdd(&Aq[((lane >> 4) * 4 + r) * ARS + g * 16 + arow], acc[g][r]);
      __syncthreads();

      // gate tail for quarter q: wave q only; other waves roll into quarter q+1.
      if (w == q) {
        f32x4 Ag[4];
#pragma unroll
        for (int g = 0; g < 4; ++g) {
          f32x4 rr = *(const f32x4*)&Aq[rg * ARS + g * 16 + cg * 4];
          f32x4 xf;
#pragma unroll
          for (int j = 0; j < 4; ++j) xf[j] = (float)xwv[g][j];
          Ag[g] = rr + xf + bvv[g];
        }
        f16x4 hv4; f32x4 o4;
#pragma unroll
        for (int j = 0; j < 4; ++j) {
          float iv = fast_sigmoid(Ag[0][j]);
          float fv = fast_sigmoid(Ag[1][j]);
          float ov = fast_sigmoid(Ag[2][j]);
          float gv = fast_tanh(Ag[3][j]);
          float cn = fv * cst[j] + iv * gv;
          cst[j] = cn;
          float hv = ov * fast_tanh(cn);
          hv4[j] = (_Float16)hv;
          o4[j] = hv;
        }
        const int row = q * 16 + rg;
        stg_coh8(&hn[row * 1024 + bid * 16 + cg * 4], hv4);
        __builtin_nontemporal_store(o4,
            (f32x4*)&out[((size_t)row * 1024 + t) * 1024 + bid * 16 + cg * 4]);
        // re-zero this quarter's Ared region for step t+1 (next atomics to it are
        // 4 syncthreads away -> ordering safe)
#pragma unroll
        for (int i = 0; i < 5; ++i) {
          int idx = lane + i * 64;
          if (idx < (16 * ARS) / 4) ((f32x4*)Aq)[idx] = (f32x4){0.f, 0.f, 0.f, 0.f};
        }
        // publish: drain h stores, then flag (relaxed write-through; round-0-proven order)
        if (lane == 0) stg_flag(flags + bid * 32 + q, (unsigned)(t + 1));
      }
    }
  }
}

// ---------------- launch ----------------

extern "C" void kernel_launch(void* const* d_in, const int* in_sizes, int n_in,
                              void* d_out, int out_size, void* d_ws, size_t ws_size,
                              hipStream_t stream) {
  const float* x  = (const float*)d_in[0];
  const float* h0 = (const float*)d_in[1];
  const float* Wx = (const float*)d_in[2];
  const float* Wh = (const float*)d_in[3];
  const float* b  = (const float*)d_in[4];
  float* out = (float*)d_out;
  char* ws = (char*)d_ws;
  if (ws_size < WS_NEED) return;  // insufficient scratch: bail (shows as poison absmax)

  unsigned int* flags = (unsigned int*)(ws + OFF_BAR);
  _Float16* h16 = (_Float16*)(ws + OFF_H16);
  _Float16* x16 = (_Float16*)(ws + OFF_X16);
  _Float16* wxT = (_Float16*)(ws + OFF_WXT);
  _Float16* whp = (_Float16*)(ws + OFF_WHP);
  _Float16* xw  = (_Float16*)(ws + OFF_XW);

  hipMemsetAsync(flags, 0, 8192, stream);
  hipLaunchKernelGGL(k_cvt_x,   dim3(65536),   dim3(256), 0, stream, x, x16);
  hipLaunchKernelGGL(k_cvt_h0,  dim3(256),     dim3(256), 0, stream, h0, h16);
  hipLaunchKernelGGL(k_tr_wx,   dim3(64, 16),  dim3(256), 0, stream, Wx, wxT);
  hipLaunchKernelGGL(k_pack_wh, dim3(2048),    dim3(256), 0, stream, Wh, whp);
  hipLaunchKernelGGL(k_gemm_xw, dim3(512, 32), dim3(256), 0, stream, x16, wxT, xw);
  hipLaunchKernelGGL(k_lstm,    dim3(64),      dim3(256), 0, stream, whp, xw, b, h16, out, flags);
}